// Round 1
// baseline (501.820 us; speedup 1.0000x reference)
//
#include <hip/hip_runtime.h>
#include <stdint.h>
#include <stddef.h>

#define NN 8192      // nodes
#define KD 256       // in_dim
#define CD 256       // out_dim*heads
#define FD 128       // out_dim
#define BI 32        // i-tile rows per block (k_gat)
#define BJ 64        // j-tile
#define JSPLIT 2
#define JCHUNK (NN / JSPLIT)

typedef __attribute__((ext_vector_type(4))) float f32x4;
typedef __attribute__((ext_vector_type(8))) short b16x8;

__device__ __forceinline__ unsigned short f2bf(float x) {
    unsigned int u = __float_as_uint(x);
    u += 0x7fffu + ((u >> 16) & 1u);
    return (unsigned short)(u >> 16);
}

// ---------------------------------------------------------------------------
// Kernel 1: T = feat @ W.T   (bf16 MFMA, fp32 out)   grid=128, block=256
// ---------------------------------------------------------------------------
__global__ __launch_bounds__(256) void k_transform(
    const float* __restrict__ feat, const float* __restrict__ W,
    float* __restrict__ T)
{
    __shared__ unsigned short a_lds[64 * 32];   // [row][granule swizzled], 4KB
    __shared__ unsigned short b_lds[256 * 32];  // [c][granule swizzled], 16KB
    const int t = threadIdx.x;
    const int wave = t >> 6, lane = t & 63;
    const int l15 = lane & 15, quad = lane >> 4;
    const int n0 = blockIdx.x * 64;
    const int ai = t >> 2, ag = t & 3;

    f32x4 acc[4][4] = {};
    for (int kc = 0; kc < 8; ++kc) {
        const int k0 = kc * 32;
        __syncthreads();
        { // stage A: features[n0+ai][k0 + ag*8 .. +7] -> bf16
            const float* src = feat + (size_t)(n0 + ai) * KD + k0 + ag * 8;
            const float4 v0 = *(const float4*)src;
            const float4 v1 = *(const float4*)(src + 4);
            union { unsigned short us[8]; b16x8 v; } pk;
            pk.us[0] = f2bf(v0.x); pk.us[1] = f2bf(v0.y);
            pk.us[2] = f2bf(v0.z); pk.us[3] = f2bf(v0.w);
            pk.us[4] = f2bf(v1.x); pk.us[5] = f2bf(v1.y);
            pk.us[6] = f2bf(v1.z); pk.us[7] = f2bf(v1.w);
            const int slot = ag ^ ((ai >> 1) & 3);
            *(b16x8*)&a_lds[ai * 32 + slot * 8] = pk.v;
        }
        for (int p = 0; p < 4; ++p) { // stage B: W[c][k0 + g*8 .. +7]
            const int G = p * 256 + t;
            const int c = G >> 2, g = G & 3;
            const float* src = W + (size_t)c * KD + k0 + g * 8;
            const float4 v0 = *(const float4*)src;
            const float4 v1 = *(const float4*)(src + 4);
            union { unsigned short us[8]; b16x8 v; } pk;
            pk.us[0] = f2bf(v0.x); pk.us[1] = f2bf(v0.y);
            pk.us[2] = f2bf(v0.z); pk.us[3] = f2bf(v0.w);
            pk.us[4] = f2bf(v1.x); pk.us[5] = f2bf(v1.y);
            pk.us[6] = f2bf(v1.z); pk.us[7] = f2bf(v1.w);
            const int slot = g ^ ((c >> 1) & 3);
            *(b16x8*)&b_lds[c * 32 + slot * 8] = pk.v;
        }
        __syncthreads();
        b16x8 af[4], bfr[4];
        for (int mt = 0; mt < 4; ++mt) {
            const int m = mt * 16 + l15;
            af[mt] = *(const b16x8*)&a_lds[m * 32 + (quad ^ ((m >> 1) & 3)) * 8];
        }
        for (int nt = 0; nt < 4; ++nt) {
            const int c = wave * 64 + nt * 16 + l15;
            bfr[nt] = *(const b16x8*)&b_lds[c * 32 + (quad ^ ((c >> 1) & 3)) * 8];
        }
        for (int mt = 0; mt < 4; ++mt)
            for (int nt = 0; nt < 4; ++nt)
                acc[mt][nt] = __builtin_amdgcn_mfma_f32_16x16x32_bf16(
                    af[mt], bfr[nt], acc[mt][nt], 0, 0, 0);
    }
    for (int mt = 0; mt < 4; ++mt)
        for (int nt = 0; nt < 4; ++nt)
            for (int r = 0; r < 4; ++r) {
                const int n = n0 + mt * 16 + quad * 4 + r;
                const int c = wave * 64 + nt * 16 + l15;
                T[(size_t)n * CD + c] = acc[mt][nt][r];
            }
}

// ---------------------------------------------------------------------------
// Kernel 1b: s[n,h], d[n,h]  — one wave per node.  grid=2048, block=256
// ---------------------------------------------------------------------------
__global__ __launch_bounds__(256) void k_scores(
    const float* __restrict__ T, const float* __restrict__ asrc,
    const float* __restrict__ adst, float* __restrict__ s, float* __restrict__ dsc)
{
    const int wave = threadIdx.x >> 6, lane = threadIdx.x & 63;
    const int n = blockIdx.x * 4 + wave;
    const float* tr = T + (size_t)n * CD;
    const float t0 = tr[lane], t1 = tr[lane + 64], t2 = tr[lane + 128], t3 = tr[lane + 192];
    float s0 = t0 * asrc[lane] + t1 * asrc[lane + 64];
    float s1 = t2 * asrc[128 + lane] + t3 * asrc[192 + lane];
    float d0 = t0 * adst[lane] + t1 * adst[lane + 64];
    float d1 = t2 * adst[128 + lane] + t3 * adst[192 + lane];
    for (int m = 1; m < 64; m <<= 1) {
        s0 += __shfl_xor(s0, m); s1 += __shfl_xor(s1, m);
        d0 += __shfl_xor(d0, m); d1 += __shfl_xor(d1, m);
    }
    if (lane == 0) {
        s[n * 2 + 0] = s0; s[n * 2 + 1] = s1;
        dsc[n * 2 + 0] = d0; dsc[n * 2 + 1] = d1;
    }
}

// ---------------------------------------------------------------------------
// Kernel 1c: Tt[c][n] = bf16(T[n][c])   grid=(128,4), block=256
// ---------------------------------------------------------------------------
__global__ __launch_bounds__(256) void k_transpose(
    const float* __restrict__ T, unsigned short* __restrict__ Tt)
{
    __shared__ float tile[64][65];
    const int t = threadIdx.x;
    const int n0 = blockIdx.x * 64, c0 = blockIdx.y * 64;
    for (int p = 0; p < 4; ++p) {
        const int idx = p * 256 + t;       // 1024 float4
        const int r = idx >> 4, q = idx & 15;
        const float4 v = *(const float4*)(T + (size_t)(n0 + r) * CD + c0 + q * 4);
        tile[r][q * 4 + 0] = v.x; tile[r][q * 4 + 1] = v.y;
        tile[r][q * 4 + 2] = v.z; tile[r][q * 4 + 3] = v.w;
    }
    __syncthreads();
    for (int p = 0; p < 16; ++p) {
        const int idx = p * 256 + t;
        const int c = idx >> 6, n = idx & 63;
        Tt[(size_t)(c0 + c) * NN + n0 + n] = f2bf(tile[n][c]);
    }
}

// ---------------------------------------------------------------------------
// Kernel 2: fused masked-softmax aggregation (flash-style, bf16 MFMA)
//   grid=(256, JSPLIT), block=256 (4 waves: (h, f-half))
// ---------------------------------------------------------------------------
__global__ __launch_bounds__(256) void k_gat(
    const int* __restrict__ adj, const unsigned short* __restrict__ Tt,
    const float* __restrict__ s, const float* __restrict__ d,
    float* __restrict__ num_part,   // [JSPLIT][NN][CD]
    float* __restrict__ den_part)   // [JSPLIT][2][NN]
{
    __shared__ unsigned short tt_lds[CD * BJ];       // 32KB, swizzled
    __shared__ unsigned short w_lds[2 * BI * BJ];    // 8KB, swizzled
    __shared__ float d_lds[2][BJ];                   // 512B

    const int t = threadIdx.x;
    const int wave = t >> 6, lane = t & 63;
    const int l15 = lane & 15, quad = lane >> 4;
    const int i0 = blockIdx.x * BI;
    const int chunk = blockIdx.y;
    const int jbase = chunk * JCHUNK;

    const int wi = t >> 3;          // 0..31 : row within i-tile
    const int j8 = t & 7;           // 0..7  : 8-wide j granule
    const int gi = i0 + wi;
    const float s0 = s[gi * 2 + 0];
    const float s1 = s[gi * 2 + 1];

    const int h = wave >> 1;        // head
    const int fh = wave & 1;        // f-half
    const int cbase = h * 128 + fh * 64;

    f32x4 acc[2][4] = {};
    float den0 = 0.f, den1 = 0.f;

    for (int jt = 0; jt < JCHUNK / BJ; ++jt) {
        const int j0 = jbase + jt * BJ;
        __syncthreads();   // prior MFMA reads done before restaging
        // stage Tt tile (bf16, swizzled): 2048 granules, 8/thread
        for (int p = 0; p < 8; ++p) {
            const int G = p * 256 + t;
            const int c = G >> 3, g = G & 7;
            const b16x8 v = *(const b16x8*)(Tt + (size_t)c * NN + j0 + g * 8);
            *(b16x8*)&tt_lds[c * BJ + ((g ^ (c & 7)) << 3)] = v;
        }
        if (t < 128) d_lds[t & 1][t >> 1] = d[(j0 + (t >> 1)) * 2 + (t & 1)];
        // adjacency: 8 ints per thread, coalesced
        const int* arow = adj + (size_t)gi * NN + j0 + j8 * 8;
        const int4 a0 = *(const int4*)arow;
        const int4 a1 = *(const int4*)(arow + 4);
        __syncthreads();   // d_lds / tt_lds ready
        // compute masked exp-leaky weights
        const int am[8] = {a0.x, a0.y, a0.z, a0.w, a1.x, a1.y, a1.z, a1.w};
        union { unsigned short us[8]; b16x8 v; } w0, w1;
        float dp0 = 0.f, dp1 = 0.f;
        for (int e = 0; e < 8; ++e) {
            const float dd0 = d_lds[0][j8 * 8 + e];
            const float dd1 = d_lds[1][j8 * 8 + e];
            float x0 = s0 + dd0;  x0 = x0 > 0.f ? x0 : 0.2f * x0;
            float x1 = s1 + dd1;  x1 = x1 > 0.f ? x1 : 0.2f * x1;
            const float e0 = am[e] != 0 ? __expf(x0) : 0.f;
            const float e1 = am[e] != 0 ? __expf(x1) : 0.f;
            dp0 += e0; dp1 += e1;
            w0.us[e] = f2bf(e0); w1.us[e] = f2bf(e1);
        }
        den0 += dp0; den1 += dp1;
        const int slot = (j8 ^ (wi & 7)) << 3;
        *(b16x8*)&w_lds[(0 * BI + wi) * BJ + slot] = w0.v;
        *(b16x8*)&w_lds[(1 * BI + wi) * BJ + slot] = w1.v;
        __syncthreads();   // w_lds ready
        // MFMA: num[i, cbase..cbase+63] += w_h @ T
        for (int ks = 0; ks < 2; ++ks) {
            const int gidx = ks * 4 + quad;
            b16x8 af[2], bfr[4];
            for (int mt = 0; mt < 2; ++mt) {
                const int m = mt * 16 + l15;
                af[mt] = *(const b16x8*)&w_lds[(h * BI + m) * BJ + ((gidx ^ (m & 7)) << 3)];
            }
            for (int nt = 0; nt < 4; ++nt) {
                const int c = cbase + nt * 16 + l15;
                bfr[nt] = *(const b16x8*)&tt_lds[c * BJ + ((gidx ^ (c & 7)) << 3)];
            }
            for (int mt = 0; mt < 2; ++mt)
                for (int nt = 0; nt < 4; ++nt)
                    acc[mt][nt] = __builtin_amdgcn_mfma_f32_16x16x32_bf16(
                        af[mt], bfr[nt], acc[mt][nt], 0, 0, 0);
        }
    }
    // reduce den over the 8 j8-lanes (lane bits 0..2)
    den0 += __shfl_xor(den0, 1); den0 += __shfl_xor(den0, 2); den0 += __shfl_xor(den0, 4);
    den1 += __shfl_xor(den1, 1); den1 += __shfl_xor(den1, 2); den1 += __shfl_xor(den1, 4);
    if (j8 == 0) {
        den_part[((size_t)chunk * 2 + 0) * NN + gi] = den0;
        den_part[((size_t)chunk * 2 + 1) * NN + gi] = den1;
    }
    float* np_ = num_part + (size_t)chunk * NN * CD;
    for (int mt = 0; mt < 2; ++mt)
        for (int nt = 0; nt < 4; ++nt)
            for (int r = 0; r < 4; ++r) {
                const int n = i0 + mt * 16 + quad * 4 + r;
                const int c = cbase + nt * 16 + l15;
                np_[(size_t)n * CD + c] = acc[mt][nt][r];
            }
}

// ---------------------------------------------------------------------------
// Kernel 3: combine partials, normalize, mean over heads.  grid=4096
// ---------------------------------------------------------------------------
__global__ __launch_bounds__(256) void k_combine(
    const float* __restrict__ num_part, const float* __restrict__ den_part,
    float* __restrict__ out)
{
    const int idx = blockIdx.x * 256 + threadIdx.x;   // NN*FD
    const int n = idx >> 7, f = idx & 127;
    const size_t row = (size_t)n * CD;
    const float n0 = num_part[row + f] + num_part[(size_t)NN * CD + row + f];
    const float n1 = num_part[row + 128 + f] + num_part[(size_t)NN * CD + row + 128 + f];
    const float d0 = den_part[n] + den_part[2 * NN + n];
    const float d1 = den_part[NN + n] + den_part[3 * NN + n];
    const float r0 = d0 != 0.f ? n0 / d0 : 0.f;
    const float r1 = d1 != 0.f ? n1 / d1 : 0.f;
    out[idx] = 0.5f * (r0 + r1);
}

// ---------------------------------------------------------------------------
extern "C" void kernel_launch(void* const* d_in, const int* in_sizes, int n_in,
                              void* d_out, int out_size, void* d_ws, size_t ws_size,
                              hipStream_t stream) {
    const float* feat = (const float*)d_in[0];
    const int*   adj  = (const int*)d_in[1];
    const float* W    = (const float*)d_in[2];
    const float* asrc = (const float*)d_in[3];
    const float* adst = (const float*)d_in[4];
    float* out = (float*)d_out;

    char* ws = (char*)d_ws;
    unsigned short* Tt = (unsigned short*)ws;                       // 4 MB
    float* T   = (float*)(ws + ((size_t)4 << 20));                  // 8 MB
    float* s   = (float*)(ws + ((size_t)12 << 20));                 // 64 KB
    float* dsc = (float*)(ws + ((size_t)12 << 20) + 65536);         // 64 KB
    float* den = (float*)(ws + ((size_t)12 << 20) + 131072);        // 128 KB
    float* nump= (float*)(ws + ((size_t)12 << 20) + 262144);        // 16 MB

    k_transform<<<128, 256, 0, stream>>>(feat, W, T);
    k_scores<<<2048, 256, 0, stream>>>(T, asrc, adst, s, dsc);
    k_transpose<<<dim3(128, 4), 256, 0, stream>>>(T, Tt);
    k_gat<<<dim3(NN / BI, JSPLIT), 256, 0, stream>>>(adj, Tt, s, dsc, nump, den);
    k_combine<<<NN * FD / 256, 256, 0, stream>>>(nump, den, out);
}

// Round 2
// 462.568 us; speedup vs baseline: 1.0849x; 1.0849x over previous
//
#include <hip/hip_runtime.h>
#include <stdint.h>
#include <stddef.h>

#define NN 8192      // nodes
#define KD 256       // in_dim
#define CD 256       // out_dim*heads
#define FD 128       // out_dim
#define BI 32        // i-tile rows per block (k_gat)
#define BJ 64        // j-tile

typedef __attribute__((ext_vector_type(4))) float f32x4;
typedef __attribute__((ext_vector_type(8))) short b16x8;

__device__ __forceinline__ unsigned short f2bf(float x) {
    unsigned int u = __float_as_uint(x);
    u += 0x7fffu + ((u >> 16) & 1u);
    return (unsigned short)(u >> 16);
}

// async global->LDS, 16B per lane; lds dest = wave-uniform base + lane*16
__device__ __forceinline__ void async16(const void* g, void* l) {
    __builtin_amdgcn_global_load_lds(
        (const __attribute__((address_space(1))) unsigned int*)g,
        (__attribute__((address_space(3))) unsigned int*)l, 16, 0, 0);
}

// ---------------------------------------------------------------------------
// Kernel 1: T = feat @ W.T (bf16 MFMA) fused with:
//   - scores s[n,h], d[n,h] from fp32 accumulators (shfl reduce)
//   - transposed bf16 output Tt[c][n]
// grid=128, block=256
// ---------------------------------------------------------------------------
__global__ __launch_bounds__(256) void k_transform(
    const float* __restrict__ feat, const float* __restrict__ W,
    const float* __restrict__ asrc, const float* __restrict__ adst,
    unsigned short* __restrict__ Tt, float* __restrict__ s, float* __restrict__ d)
{
    __shared__ unsigned short a_lds[64 * 32];    // 4KB
    __shared__ unsigned short b_lds[256 * 32];   // 16KB
    __shared__ unsigned short tr_lds[256 * 72];  // 36KB (stride 72 = 144B: 16B-aligned rows, no conflicts)
    __shared__ float sc_lds[4][64];              // 1KB
    __shared__ float dc_lds[4][64];              // 1KB

    const int t = threadIdx.x;
    const int wave = t >> 6, lane = t & 63;
    const int l15 = lane & 15, quad = lane >> 4;
    const int n0 = blockIdx.x * 64;
    const int ai = t >> 2, ag = t & 3;

    f32x4 acc[4][4] = {};
    for (int kc = 0; kc < 8; ++kc) {
        const int k0 = kc * 32;
        __syncthreads();
        { // stage A: features[n0+ai][k0 + ag*8 .. +7] -> bf16
            const float* src = feat + (size_t)(n0 + ai) * KD + k0 + ag * 8;
            const float4 v0 = *(const float4*)src;
            const float4 v1 = *(const float4*)(src + 4);
            union { unsigned short us[8]; b16x8 v; } pk;
            pk.us[0] = f2bf(v0.x); pk.us[1] = f2bf(v0.y);
            pk.us[2] = f2bf(v0.z); pk.us[3] = f2bf(v0.w);
            pk.us[4] = f2bf(v1.x); pk.us[5] = f2bf(v1.y);
            pk.us[6] = f2bf(v1.z); pk.us[7] = f2bf(v1.w);
            const int slot = ag ^ ((ai >> 1) & 3);
            *(b16x8*)&a_lds[ai * 32 + slot * 8] = pk.v;
        }
        for (int p = 0; p < 4; ++p) { // stage B: W[c][k0 + g*8 .. +7]
            const int G = p * 256 + t;
            const int c = G >> 2, g = G & 3;
            const float* src = W + (size_t)c * KD + k0 + g * 8;
            const float4 v0 = *(const float4*)src;
            const float4 v1 = *(const float4*)(src + 4);
            union { unsigned short us[8]; b16x8 v; } pk;
            pk.us[0] = f2bf(v0.x); pk.us[1] = f2bf(v0.y);
            pk.us[2] = f2bf(v0.z); pk.us[3] = f2bf(v0.w);
            pk.us[4] = f2bf(v1.x); pk.us[5] = f2bf(v1.y);
            pk.us[6] = f2bf(v1.z); pk.us[7] = f2bf(v1.w);
            const int slot = g ^ ((c >> 1) & 3);
            *(b16x8*)&b_lds[c * 32 + slot * 8] = pk.v;
        }
        __syncthreads();
        b16x8 af[4], bfr[4];
        for (int mt = 0; mt < 4; ++mt) {
            const int m = mt * 16 + l15;
            af[mt] = *(const b16x8*)&a_lds[m * 32 + (quad ^ ((m >> 1) & 3)) * 8];
        }
        for (int nt = 0; nt < 4; ++nt) {
            const int c = wave * 64 + nt * 16 + l15;
            bfr[nt] = *(const b16x8*)&b_lds[c * 32 + (quad ^ ((c >> 1) & 3)) * 8];
        }
        for (int mt = 0; mt < 4; ++mt)
            for (int nt = 0; nt < 4; ++nt)
                acc[mt][nt] = __builtin_amdgcn_mfma_f32_16x16x32_bf16(
                    af[mt], bfr[nt], acc[mt][nt], 0, 0, 0);
    }

    // ---- epilogue: scores (fp32) + transposed bf16 store ----
    float aS[4], aD[4];
    for (int nt = 0; nt < 4; ++nt) {
        const int c = wave * 64 + nt * 16 + l15;
        aS[nt] = asrc[c]; aD[nt] = adst[c];
    }
    for (int mt = 0; mt < 4; ++mt)
        for (int r = 0; r < 4; ++r) {
            float vs = 0.f, vd = 0.f;
            for (int nt = 0; nt < 4; ++nt) {
                const float x = acc[mt][nt][r];
                vs += x * aS[nt]; vd += x * aD[nt];
            }
            vs += __shfl_xor(vs, 1); vd += __shfl_xor(vd, 1);
            vs += __shfl_xor(vs, 2); vd += __shfl_xor(vd, 2);
            vs += __shfl_xor(vs, 4); vd += __shfl_xor(vd, 4);
            vs += __shfl_xor(vs, 8); vd += __shfl_xor(vd, 8);
            if (l15 == 0) {
                const int nl = mt * 16 + quad * 4 + r;
                sc_lds[wave][nl] = vs; dc_lds[wave][nl] = vd;
            }
        }
    for (int mt = 0; mt < 4; ++mt)
        for (int nt = 0; nt < 4; ++nt)
            for (int r = 0; r < 4; ++r) {
                const int c = wave * 64 + nt * 16 + l15;
                const int n = mt * 16 + quad * 4 + r;
                tr_lds[c * 72 + n] = f2bf(acc[mt][nt][r]);
            }
    __syncthreads();
    if (t < 128) {
        const int n = t >> 1, h = t & 1;
        s[(size_t)(n0 + n) * 2 + h] = sc_lds[h * 2][n] + sc_lds[h * 2 + 1][n];
        d[(size_t)(n0 + n) * 2 + h] = dc_lds[h * 2][n] + dc_lds[h * 2 + 1][n];
    }
    for (int p = 0; p < 8; ++p) {
        const int idx = p * 256 + t;       // 2048 granules
        const int c = idx >> 3, g = idx & 7;
        *(b16x8*)(Tt + (size_t)c * NN + n0 + g * 8) = *(const b16x8*)&tr_lds[c * 72 + g * 8];
    }
}

// ---------------------------------------------------------------------------
// Kernel 2: fused masked-softmax aggregation (flash-style, bf16 MFMA)
//   grid=(256, jsplit), block=256 (4 waves: (h, f-half))
//   LDS = 40960 exactly -> 4 blocks/CU; async global_load_lds for Tt tile
// ---------------------------------------------------------------------------
__global__ __launch_bounds__(256, 4) void k_gat(
    const int* __restrict__ adj, const unsigned short* __restrict__ Tt,
    const float* __restrict__ s, const float* __restrict__ d,
    float* __restrict__ num_part,   // [jsplit][NN][CD]
    float* __restrict__ den_part,   // [jsplit][2][NN]
    int jchunk)
{
    __shared__ unsigned short tt_lds[CD * BJ];       // 32KB (swizzled via global addr perm)
    __shared__ unsigned short w_lds[2 * BI * BJ];    // 8KB, swizzled

    const int t = threadIdx.x;
    const int wave = t >> 6, lane = t & 63;
    const int l15 = lane & 15, quad = lane >> 4;
    const int i0 = blockIdx.x * BI;
    const int chunk = blockIdx.y;
    const int jbase = chunk * jchunk;

    const int wi = t >> 3;          // 0..31 : row within i-tile
    const int j8 = t & 7;           // 0..7  : 8-wide j granule
    const int gi = i0 + wi;
    const float s0 = s[(size_t)gi * 2 + 0];
    const float s1 = s[(size_t)gi * 2 + 1];

    const int h = wave >> 1;        // head
    const int fh = wave & 1;        // f-half
    const int cbase = h * 128 + fh * 64;

    f32x4 acc[2][4] = {};
    float den0 = 0.f, den1 = 0.f;
    const int njt = jchunk / BJ;

    for (int jt = 0; jt < njt; ++jt) {
        const int j0 = jbase + jt * BJ;
        __syncthreads();   // prior MFMA reads of tt_lds/w_lds done
        // --- short loads FIRST (vmcnt is FIFO: exp can start without tt) ---
        const int* arow = adj + (size_t)gi * NN + j0 + j8 * 8;
        const int4 a0 = *(const int4*)arow;
        const int4 a1 = *(const int4*)(arow + 4);
        const float4* dvp = (const float4*)(d + (size_t)(j0 + j8 * 8) * 2);
        union { float4 v[4]; float f[16]; } dv;
        dv.v[0] = dvp[0]; dv.v[1] = dvp[1]; dv.v[2] = dvp[2]; dv.v[3] = dvp[3];
        // --- async Tt tile stage (global-addr permuted to keep XOR swizzle) ---
        for (int p = 0; p < 8; ++p) {
            const int G = (p * 4 + wave) * 64 + lane;   // LDS granule index (linear)
            const int c = G >> 3, gt = G & 7;
            const int g = gt ^ (c & 7);                 // inverse perm on global side
            async16(Tt + (size_t)c * NN + j0 + g * 8,
                    (char*)tt_lds + (size_t)(p * 4 + wave) * 1024);
        }
        // --- masked exp(leaky) weights (overlaps the async tt loads) ---
        const int am[8] = {a0.x, a0.y, a0.z, a0.w, a1.x, a1.y, a1.z, a1.w};
        union { unsigned short us[8]; b16x8 v; } w0, w1;
        float dp0 = 0.f, dp1 = 0.f;
        for (int e = 0; e < 8; ++e) {
            float x0 = s0 + dv.f[e * 2 + 0];  x0 = x0 > 0.f ? x0 : 0.2f * x0;
            float x1 = s1 + dv.f[e * 2 + 1];  x1 = x1 > 0.f ? x1 : 0.2f * x1;
            const float e0 = am[e] != 0 ? __expf(x0) : 0.f;
            const float e1 = am[e] != 0 ? __expf(x1) : 0.f;
            dp0 += e0; dp1 += e1;
            w0.us[e] = f2bf(e0); w1.us[e] = f2bf(e1);
        }
        den0 += dp0; den1 += dp1;
        const int slot = (j8 ^ (wi & 7)) << 3;
        *(b16x8*)&w_lds[(0 * BI + wi) * BJ + slot] = w0.v;
        *(b16x8*)&w_lds[(1 * BI + wi) * BJ + slot] = w1.v;
        __syncthreads();   // w_lds ready; drains async tt loads
        // --- MFMA: num[i, cbase..cbase+63] += w_h @ T ---
        for (int ks = 0; ks < 2; ++ks) {
            const int gidx = ks * 4 + quad;
            b16x8 af[2], bfr[4];
            for (int mt = 0; mt < 2; ++mt) {
                const int m = mt * 16 + l15;
                af[mt] = *(const b16x8*)&w_lds[(h * BI + m) * BJ + ((gidx ^ (m & 7)) << 3)];
            }
            for (int nt = 0; nt < 4; ++nt) {
                const int c = cbase + nt * 16 + l15;
                bfr[nt] = *(const b16x8*)&tt_lds[c * BJ + ((gidx ^ (c & 7)) << 3)];
            }
            for (int mt = 0; mt < 2; ++mt)
                for (int nt = 0; nt < 4; ++nt)
                    acc[mt][nt] = __builtin_amdgcn_mfma_f32_16x16x32_bf16(
                        af[mt], bfr[nt], acc[mt][nt], 0, 0, 0);
        }
    }
    // reduce den over the 8 j8-lanes (lane bits 0..2)
    den0 += __shfl_xor(den0, 1); den0 += __shfl_xor(den0, 2); den0 += __shfl_xor(den0, 4);
    den1 += __shfl_xor(den1, 1); den1 += __shfl_xor(den1, 2); den1 += __shfl_xor(den1, 4);
    if (j8 == 0) {
        den_part[((size_t)chunk * 2 + 0) * NN + gi] = den0;
        den_part[((size_t)chunk * 2 + 1) * NN + gi] = den1;
    }
    float* np_ = num_part + (size_t)chunk * NN * CD;
    for (int mt = 0; mt < 2; ++mt)
        for (int nt = 0; nt < 4; ++nt)
            for (int r = 0; r < 4; ++r) {
                const int n = i0 + mt * 16 + quad * 4 + r;
                const int c = cbase + nt * 16 + l15;
                np_[(size_t)n * CD + c] = acc[mt][nt][r];
            }
}

// ---------------------------------------------------------------------------
// Kernel 3: combine partials, normalize, mean over heads.  grid=4096
// ---------------------------------------------------------------------------
__global__ __launch_bounds__(256) void k_combine(
    const float* __restrict__ num_part, const float* __restrict__ den_part,
    float* __restrict__ out, int jsplit)
{
    const int idx = blockIdx.x * 256 + threadIdx.x;   // NN*FD
    const int n = idx >> 7, f = idx & 127;
    const size_t row = (size_t)n * CD;
    float n0 = 0.f, n1 = 0.f, d0 = 0.f, d1 = 0.f;
    for (int c = 0; c < jsplit; ++c) {
        const size_t base = (size_t)c * NN * CD;
        n0 += num_part[base + row + f];
        n1 += num_part[base + row + 128 + f];
        d0 += den_part[((size_t)c * 2 + 0) * NN + n];
        d1 += den_part[((size_t)c * 2 + 1) * NN + n];
    }
    const float r0 = d0 != 0.f ? n0 / d0 : 0.f;
    const float r1 = d1 != 0.f ? n1 / d1 : 0.f;
    out[idx] = 0.5f * (r0 + r1);
}

// ---------------------------------------------------------------------------
extern "C" void kernel_launch(void* const* d_in, const int* in_sizes, int n_in,
                              void* d_out, int out_size, void* d_ws, size_t ws_size,
                              hipStream_t stream) {
    const float* feat = (const float*)d_in[0];
    const int*   adj  = (const int*)d_in[1];
    const float* W    = (const float*)d_in[2];
    const float* asrc = (const float*)d_in[3];
    const float* adst = (const float*)d_in[4];
    float* out = (float*)d_out;

    // jsplit=4 needs 8MB + 4*8MB = 40MB of ws; fall back to 2 (24MB) if short
    const int jsplit = (ws_size >= ((size_t)40 << 20)) ? 4 : 2;
    const int jchunk = NN / jsplit;

    char* ws = (char*)d_ws;
    unsigned short* Tt = (unsigned short*)ws;                       // 4 MB
    float* s    = (float*)(ws + ((size_t)4 << 20));                 // 64 KB
    float* dsc  = (float*)(ws + ((size_t)4 << 20) + (64 << 10));    // 64 KB
    float* den  = (float*)(ws + ((size_t)4 << 20) + (128 << 10));   // <=256 KB
    float* nump = (float*)(ws + ((size_t)8 << 20));                 // jsplit*8 MB

    k_transform<<<128, 256, 0, stream>>>(feat, W, asrc, adst, Tt, s, dsc);
    k_gat<<<dim3(NN / BI, jsplit), 256, 0, stream>>>(adj, Tt, s, dsc, nump, den, jchunk);
    k_combine<<<NN * FD / 256, 256, 0, stream>>>(nump, den, out, jsplit);
}